// Round 9
// baseline (10404.413 us; speedup 1.0000x reference)
//
#include <hip/hip_runtime.h>
#include <cstdint>
#include <cstddef>

typedef unsigned int u32;
typedef unsigned long long u64;

#define NBATCH 8192
#define SEQLEN 64
#define ZDIM   256
#define HDIM   64
#define NNEUR  128
#define EMID   160
#define DMID   96
#define TILE   32

__device__ __forceinline__ u32 rotl32(u32 v, int s){ return (v << s) | (v >> (32 - s)); }

// Threefry2x32, 20 rounds — exact JAX schedule.
__device__ __forceinline__ void tf2x32(u32 k0, u32 k1, u32 x0, u32 x1, u32& y0, u32& y1){
  u32 ks2 = k0 ^ k1 ^ 0x1BD11BDAu;
  x0 += k0; x1 += k1;
#define TF_R(r) { x0 += x1; x1 = rotl32(x1, (r)); x1 ^= x0; }
  TF_R(13) TF_R(15) TF_R(26) TF_R(6)
  x0 += k1;  x1 += ks2 + 1u;
  TF_R(17) TF_R(29) TF_R(16) TF_R(24)
  x0 += ks2; x1 += k0 + 2u;
  TF_R(13) TF_R(15) TF_R(26) TF_R(6)
  x0 += k0;  x1 += k1 + 3u;
  TF_R(17) TF_R(29) TF_R(16) TF_R(24)
  x0 += k1;  x1 += ks2 + 4u;
  TF_R(13) TF_R(15) TF_R(26) TF_R(6)
  x0 += ks2; x1 += k0 + 5u;
#undef TF_R
  y0 = x0; y1 = x1;
}

__device__ __forceinline__ float sigmf(float x){ return 1.0f / (1.0f + expf(-x)); }

__device__ __forceinline__ float dot4acc(float4 w, float4 v, float a){
  a = fmaf(w.x, v.x, a); a = fmaf(w.y, v.y, a);
  a = fmaf(w.z, v.z, a); a = fmaf(w.w, v.w, a);
  return a;
}

__global__ void __launch_bounds__(512, 1)
bar_decoder_kernel(const float* __restrict__ z,
                   const float* __restrict__ W_enc1, const float* __restrict__ b_enc1,
                   const float* __restrict__ W_enc2, const float* __restrict__ b_enc2,
                   const float* __restrict__ W_ih0,  const float* __restrict__ W_hh0,
                   const float* __restrict__ b_ih0,  const float* __restrict__ b_hh0,
                   const float* __restrict__ W_ih1,  const float* __restrict__ W_hh1,
                   const float* __restrict__ b_ih1,  const float* __restrict__ b_hh1,
                   const float* __restrict__ W_dec1, const float* __restrict__ b_dec1,
                   const float* __restrict__ W_dec2, const float* __restrict__ b_dec2,
                   float* __restrict__ out)   // f32: weights [0,2^26), samples at 2^26
{
  // LDS (bytes), 62464 total:
  //   h0b [2][32][64] @0      (16384)   double-buffered
  //   h1b [2][32][64] @16384  (16384)   double-buffered
  //   d1  [32][100]   @32768  (12800)
  //   lg  [32][128]   @45568  (16384)
  //   keyw[64][2]     @61952  (512)
  // encoder overlays: encv [32][68] @0; mid [32][164] @32768
  __shared__ __align__(16) char buf[62464];
  float* h0b  = (float*)buf;
  float* h1b  = (float*)(buf + 16384);
  float* d1   = (float*)(buf + 32768);
  float* lgb  = (float*)(buf + 45568);
  u32*   keyw = (u32*)  (buf + 61952);
  float* mid  = (float*)(buf + 32768);
  float* encv = (float*)buf;

  const int t     = threadIdx.x;
  const int tile0 = blockIdx.x * TILE;
  const int lane  = t & 63;
  const int kq    = lane >> 4;              // K-quarter 0..3 (lane bits 4-5)
  const int wv    = t >> 6;
  const int j     = (lane & 15) | ((wv & 3) << 4);  // hidden unit 0..63
  const int bh    = wv >> 2;                // batch half (16 each)
  const int dn    = t & 127;                // dec row
  const int dq    = t >> 7;                 // dec batch group 0..3

  // ---------------- encoder: mid = relu(z @ Wenc1^T + b1) ----------------
  if (t < EMID) {
    float acc[TILE];
    float bb = b_enc1[t];
    #pragma unroll
    for (int b = 0; b < TILE; ++b) acc[b] = bb;
    const float4* wr = (const float4*)(W_enc1 + (size_t)t * ZDIM);
    #pragma unroll 2
    for (int k4 = 0; k4 < 64; ++k4){
      float4 w = wr[k4];
      for (int b = 0; b < TILE; ++b){
        float4 zv = *(const float4*)(z + (size_t)(tile0 + b) * ZDIM + k4 * 4);
        acc[b] = dot4acc(w, zv, acc[b]);
      }
    }
    #pragma unroll
    for (int b = 0; b < TILE; ++b) mid[b * 164 + t] = fmaxf(acc[b], 0.0f);
  }
  __syncthreads();

  // ---------------- enc = mid @ Wenc2^T + b2 -> encv ----------------
  if (t < HDIM) {
    float acc[TILE];
    float bb = b_enc2[t];
    #pragma unroll
    for (int b = 0; b < TILE; ++b) acc[b] = bb;
    const float4* wr = (const float4*)(W_enc2 + (size_t)t * EMID);
    #pragma unroll 2
    for (int k4 = 0; k4 < 40; ++k4){
      float4 w = wr[k4];
      for (int b = 0; b < TILE; ++b){
        float4 v = *(const float4*)(mid + b * 164 + k4 * 4);
        acc[b] = dot4acc(w, v, acc[b]);
      }
    }
    #pragma unroll
    for (int b = 0; b < TILE; ++b) encv[b * 68 + t] = acc[b];
  }
  __syncthreads();

  // ---------------- xg0 for this thread's 4 write-batches, 4 gate rows ----------------
  // write-batches: b = bh*16 + bgrp*4 + kq  (bgrp = 0..3); rows g*64+j
  float xg0r[4][4];   // [g][bgrp]
  {
    #pragma unroll
    for (int g = 0; g < 4; ++g){
      const int row = g * 64 + j;
      const float bb = b_ih0[row] + b_hh0[row];
      const float4* wr = (const float4*)(W_ih0 + (size_t)row * HDIM);
      float a0[4];
      #pragma unroll
      for (int q = 0; q < 4; ++q) a0[q] = bb;
      #pragma unroll
      for (int k4 = 0; k4 < 16; ++k4){
        float4 w = wr[k4];
        #pragma unroll
        for (int q = 0; q < 4; ++q){
          const int b = bh * 16 + q * 4 + kq;
          float4 ev = *(const float4*)(encv + b * 68 + k4 * 4);
          a0[q] = dot4acc(w, ev, a0[q]);
        }
      }
      #pragma unroll
      for (int q = 0; q < 4; ++q) xg0r[g][q] = a0[q];
    }
  }

  // ---------------- persistent registers: quarter-rows of the 3 LSTM matrices ----------------
  float4 w0r[4][4], w1r[4][4], w2r[4][4];   // [g][k'] — k = kq*16 + k'*4 ..
  float bias1r4[4];
  {
    #pragma unroll
    for (int g = 0; g < 4; ++g){
      const size_t row = (size_t)(g * 64 + j);
      const float4* p0 = (const float4*)(W_hh0 + row * HDIM);
      const float4* p1 = (const float4*)(W_ih1 + row * HDIM);
      const float4* p2 = (const float4*)(W_hh1 + row * HDIM);
      #pragma unroll
      for (int k = 0; k < 4; ++k){
        w0r[g][k] = p0[kq * 4 + k];
        w1r[g][k] = p1[kq * 4 + k];
        w2r[g][k] = p2[kq * 4 + k];
      }
      bias1r4[g] = b_ih1[row] + b_hh1[row];
    }
  }
  const float bd1 = (dn < DMID) ? b_dec1[dn] : 0.0f;
  const float bd2 = b_dec2[dn];

  __syncthreads();   // encv reads complete before h-buffer zero-init (overlay)

  for (int i = t; i < 2 * 32 * 64; i += 512){ h0b[i] = 0.0f; h1b[i] = 0.0f; }
  if (t < SEQLEN) {
    u32 a0, a1;
    tf2x32(0u, 42u, 0u, (u32)t, a0, a1);   // partitionable split of key(42)
    keyw[2 * t] = a0; keyw[2 * t + 1] = a1;
  }
  float c0r[4] = {0,0,0,0}, c1r[4] = {0,0,0,0};
  __syncthreads();

  for (int s = 0; s < SEQLEN; ++s){
    const int cur = s & 1, prv = cur ^ 1;
    float* h0c = h0b + cur * 2048;
    float* h0p = h0b + prv * 2048;
    float* h1c = h1b + cur * 2048;
    float* h1p = h1b + prv * 2048;

    // ---------- A: layer0 gates + combine (fused) ----------
    #pragma unroll
    for (int bgrp = 0; bgrp < 4; ++bgrp){
      const int bbase = bh * 16 + bgrp * 4;
      float acc[4][4];   // [g][bi]
      #pragma unroll
      for (int g = 0; g < 4; ++g)
        #pragma unroll
        for (int bi = 0; bi < 4; ++bi) acc[g][bi] = 0.0f;
      #pragma unroll
      for (int k = 0; k < 4; ++k){
        #pragma unroll
        for (int bi = 0; bi < 4; ++bi){
          float4 hv = *(const float4*)(h0p + (bbase + bi) * 64 + kq * 16 + k * 4);
          #pragma unroll
          for (int g = 0; g < 4; ++g) acc[g][bi] = dot4acc(w0r[g][k], hv, acc[g][bi]);
        }
      }
      // butterfly over kq (lane bits 4,5): every lane gets the full K-sum
      #pragma unroll
      for (int g = 0; g < 4; ++g)
        #pragma unroll
        for (int bi = 0; bi < 4; ++bi){
          acc[g][bi] += __shfl_xor(acc[g][bi], 16);
          acc[g][bi] += __shfl_xor(acc[g][bi], 32);
        }
      // writer: this lane combines batch bbase+kq (select bi==kq statically)
      float gsum[4];
      #pragma unroll
      for (int g = 0; g < 4; ++g){
        float v = acc[g][0];
        v = (kq == 1) ? acc[g][1] : v;
        v = (kq == 2) ? acc[g][2] : v;
        v = (kq == 3) ? acc[g][3] : v;
        gsum[g] = v;
      }
      const int b = bbase + kq;
      float ig = sigmf(xg0r[0][bgrp] + gsum[0]);
      float fg = sigmf(xg0r[1][bgrp] + gsum[1]);
      float gg = tanhf(xg0r[2][bgrp] + gsum[2]);
      float og = sigmf(xg0r[3][bgrp] + gsum[3]);
      float c  = fg * c0r[bgrp] + ig * gg;
      c0r[bgrp] = c;
      h0c[b * 64 + j] = og * tanhf(c);
    }
    __syncthreads();   // 1: h0c visible

    // ---------- B: layer1 gates + combine (fused; two matrices) ----------
    #pragma unroll
    for (int bgrp = 0; bgrp < 4; ++bgrp){
      const int bbase = bh * 16 + bgrp * 4;
      float acc[4][4];
      #pragma unroll
      for (int g = 0; g < 4; ++g)
        #pragma unroll
        for (int bi = 0; bi < 4; ++bi) acc[g][bi] = 0.0f;
      #pragma unroll
      for (int k = 0; k < 4; ++k){
        #pragma unroll
        for (int bi = 0; bi < 4; ++bi){
          float4 hv = *(const float4*)(h0c + (bbase + bi) * 64 + kq * 16 + k * 4);
          #pragma unroll
          for (int g = 0; g < 4; ++g) acc[g][bi] = dot4acc(w1r[g][k], hv, acc[g][bi]);
        }
      }
      #pragma unroll
      for (int k = 0; k < 4; ++k){
        #pragma unroll
        for (int bi = 0; bi < 4; ++bi){
          float4 hv = *(const float4*)(h1p + (bbase + bi) * 64 + kq * 16 + k * 4);
          #pragma unroll
          for (int g = 0; g < 4; ++g) acc[g][bi] = dot4acc(w2r[g][k], hv, acc[g][bi]);
        }
      }
      #pragma unroll
      for (int g = 0; g < 4; ++g)
        #pragma unroll
        for (int bi = 0; bi < 4; ++bi){
          acc[g][bi] += __shfl_xor(acc[g][bi], 16);
          acc[g][bi] += __shfl_xor(acc[g][bi], 32);
        }
      float gsum[4];
      #pragma unroll
      for (int g = 0; g < 4; ++g){
        float v = acc[g][0];
        v = (kq == 1) ? acc[g][1] : v;
        v = (kq == 2) ? acc[g][2] : v;
        v = (kq == 3) ? acc[g][3] : v;
        gsum[g] = v;
      }
      const int b = bbase + kq;
      float ig = sigmf(bias1r4[0] + gsum[0]);
      float fg = sigmf(bias1r4[1] + gsum[1]);
      float gg = tanhf(bias1r4[2] + gsum[2]);
      float og = sigmf(bias1r4[3] + gsum[3]);
      float c  = fg * c1r[bgrp] + ig * gg;
      c1r[bgrp] = c;
      h1c[b * 64 + j] = og * tanhf(c);
    }
    __syncthreads();   // 2: h1c visible

    // ---------- C: dec1 = relu(h1 @ Wdec1^T + b) ----------
    if (dn < DMID){
      float a[8];
      #pragma unroll
      for (int q = 0; q < 8; ++q) a[q] = bd1;
      const float4* wr = (const float4*)(W_dec1 + (size_t)dn * HDIM);
      #pragma unroll
      for (int k4 = 0; k4 < 16; ++k4){
        float4 w = wr[k4];
        #pragma unroll
        for (int q = 0; q < 8; ++q){
          float4 hv = *(const float4*)(h1c + (dq * 8 + q) * 64 + k4 * 4);
          a[q] = dot4acc(w, hv, a[q]);
        }
      }
      #pragma unroll
      for (int q = 0; q < 8; ++q) d1[(dq * 8 + q) * 100 + dn] = fmaxf(a[q], 0.0f);
    }
    __syncthreads();   // 3: d1 visible

    // ---------- D: dec2 logits ----------
    {
      float a[8];
      #pragma unroll
      for (int q = 0; q < 8; ++q) a[q] = bd2;
      const float4* wr = (const float4*)(W_dec2 + (size_t)dn * DMID);
      #pragma unroll
      for (int k4 = 0; k4 < 24; ++k4){
        float4 w = wr[k4];
        #pragma unroll
        for (int q = 0; q < 8; ++q){
          float4 dv = *(const float4*)(d1 + (dq * 8 + q) * 100 + k4 * 4);
          a[q] = dot4acc(w, dv, a[q]);
        }
      }
      #pragma unroll
      for (int q = 0; q < 8; ++q) lgb[(dq * 8 + q) * 128 + dn] = a[q];
    }
    __syncthreads();   // 4: lg visible

    // ---------- E: softmax + categorical sample (no trailing barrier) ----------
    {
      const int bl  = t >> 4;
      const int s16 = t & 15;
      const int bgl = tile0 + bl;

      float lv[8];
      {
        const float4* lrow = (const float4*)(lgb + bl * 128 + s16 * 8);
        float4 a = lrow[0], b = lrow[1];
        lv[0]=a.x; lv[1]=a.y; lv[2]=a.z; lv[3]=a.w;
        lv[4]=b.x; lv[5]=b.y; lv[6]=b.z; lv[7]=b.w;
      }
      float lmax = lv[0];
      #pragma unroll
      for (int i = 1; i < 8; ++i) lmax = fmaxf(lmax, lv[i]);
      #pragma unroll
      for (int m = 1; m < 16; m <<= 1) lmax = fmaxf(lmax, __shfl_xor(lmax, m));

      float esum = 0.0f; float ev[8];
      #pragma unroll
      for (int i = 0; i < 8; ++i){
        float e = expf(lv[i] - lmax);
        ev[i] = e; esum += e;
      }
      #pragma unroll
      for (int m = 1; m < 16; m <<= 1) esum += __shfl_xor(esum, m);
      float inv = 1.0f / esum;

      float4* wrow = (float4*)(out + (u64)bgl * (SEQLEN * NNEUR)
                                   + (u64)s * NNEUR + (u64)(s16 * 8));
      wrow[0] = make_float4(ev[0]*inv, ev[1]*inv, ev[2]*inv, ev[3]*inv);
      wrow[1] = make_float4(ev[4]*inv, ev[5]*inv, ev[6]*inv, ev[7]*inv);

      const u32 kk0 = keyw[2 * s];
      const u32 kk1 = keyw[2 * s + 1];
      float vmax = -3.402823466e38f; int vidx = 0;
      #pragma unroll
      for (int i = 0; i < 8; ++i){
        const int n = s16 * 8 + i;
        u32 y0, y1;
        tf2x32(kk0, kk1, 0u, (u32)(bgl * 128 + n), y0, y1);
        u32 bits = y0 ^ y1;
        float f  = __uint_as_float((bits >> 9) | 0x3f800000u) - 1.0f;
        float u  = f + 1.1754943508222875e-38f;   // f*(1-tiny)+tiny in f32
        u = fmaxf(u, 1.1754943508222875e-38f);
        float gmb = -logf(-logf(u));
        float val = gmb + lv[i];
        if (val > vmax){ vmax = val; vidx = n; }
      }
      #pragma unroll
      for (int m = 1; m < 16; m <<= 1){
        float ov = __shfl_xor(vmax, m);
        int   oi = __shfl_xor(vidx, m);
        if (ov > vmax || (ov == vmax && oi < vidx)){ vmax = ov; vidx = oi; }
      }
      if (s16 == 0)
        out[(u64)NBATCH * SEQLEN * NNEUR + (u64)bgl * SEQLEN + (u64)s] = (float)vidx;
    }
    // no trailing barrier: next phase to touch lg is D(s+1), 3 barriers away;
    // A(s+1) touches only h0b (disjoint from E's lg reads / out writes)
  }
}

extern "C" void kernel_launch(void* const* d_in, const int* in_sizes, int n_in,
                              void* d_out, int out_size, void* d_ws, size_t ws_size,
                              hipStream_t stream) {
  (void)in_sizes; (void)n_in; (void)out_size; (void)d_ws; (void)ws_size;
  const float* z      = (const float*)d_in[0];
  // d_in[1]=score_tensor, d_in[2]=train: unused by the reference math
  const float* W_enc1 = (const float*)d_in[3];
  const float* b_enc1 = (const float*)d_in[4];
  const float* W_enc2 = (const float*)d_in[5];
  const float* b_enc2 = (const float*)d_in[6];
  const float* W_ih0  = (const float*)d_in[7];
  const float* W_hh0  = (const float*)d_in[8];
  const float* b_ih0  = (const float*)d_in[9];
  const float* b_hh0  = (const float*)d_in[10];
  const float* W_ih1  = (const float*)d_in[11];
  const float* W_hh1  = (const float*)d_in[12];
  const float* b_ih1  = (const float*)d_in[13];
  const float* b_hh1  = (const float*)d_in[14];
  const float* W_dec1 = (const float*)d_in[15];
  const float* b_dec1 = (const float*)d_in[16];
  const float* W_dec2 = (const float*)d_in[17];
  const float* b_dec2 = (const float*)d_in[18];

  float* out = (float*)d_out;

  dim3 grid(NBATCH / TILE);   // 256 blocks -> 1 per CU
  dim3 blk(512);
  hipLaunchKernelGGL(bar_decoder_kernel, grid, blk, 0, stream,
                     z, W_enc1, b_enc1, W_enc2, b_enc2,
                     W_ih0, W_hh0, b_ih0, b_hh0,
                     W_ih1, W_hh1, b_ih1, b_hh1,
                     W_dec1, b_dec1, W_dec2, b_dec2,
                     out);
}

// Round 10
// 3650.713 us; speedup vs baseline: 2.8500x; 2.8500x over previous
//
#include <hip/hip_runtime.h>
#include <cstdint>
#include <cstddef>

typedef unsigned int u32;
typedef unsigned long long u64;

#define NBATCH 8192
#define SEQLEN 64
#define ZDIM   256
#define HDIM   64
#define NNEUR  128
#define EMID   160
#define DMID   96
#define TILE   16

__device__ __forceinline__ u32 rotl32(u32 v, int s){ return (v << s) | (v >> (32 - s)); }

// Threefry2x32, 20 rounds — exact JAX schedule.
__device__ __forceinline__ void tf2x32(u32 k0, u32 k1, u32 x0, u32 x1, u32& y0, u32& y1){
  u32 ks2 = k0 ^ k1 ^ 0x1BD11BDAu;
  x0 += k0; x1 += k1;
#define TF_R(r) { x0 += x1; x1 = rotl32(x1, (r)); x1 ^= x0; }
  TF_R(13) TF_R(15) TF_R(26) TF_R(6)
  x0 += k1;  x1 += ks2 + 1u;
  TF_R(17) TF_R(29) TF_R(16) TF_R(24)
  x0 += ks2; x1 += k0 + 2u;
  TF_R(13) TF_R(15) TF_R(26) TF_R(6)
  x0 += k0;  x1 += k1 + 3u;
  TF_R(17) TF_R(29) TF_R(16) TF_R(24)
  x0 += k1;  x1 += ks2 + 4u;
  TF_R(13) TF_R(15) TF_R(26) TF_R(6)
  x0 += ks2; x1 += k0 + 5u;
#undef TF_R
  y0 = x0; y1 = x1;
}

__device__ __forceinline__ float sigmf(float x){ return 1.0f / (1.0f + expf(-x)); }

__device__ __forceinline__ float dot4acc(float4 w, float4 v, float a){
  a = fmaf(w.x, v.x, a); a = fmaf(w.y, v.y, a);
  a = fmaf(w.z, v.z, a); a = fmaf(w.w, v.w, a);
  return a;
}

__global__ void __launch_bounds__(256, 2)
bar_decoder_kernel(const float* __restrict__ z,
                   const float* __restrict__ W_enc1, const float* __restrict__ b_enc1,
                   const float* __restrict__ W_enc2, const float* __restrict__ b_enc2,
                   const float* __restrict__ W_ih0,  const float* __restrict__ W_hh0,
                   const float* __restrict__ b_ih0,  const float* __restrict__ b_hh0,
                   const float* __restrict__ W_ih1,  const float* __restrict__ W_hh1,
                   const float* __restrict__ b_ih1,  const float* __restrict__ b_hh1,
                   const float* __restrict__ W_dec1, const float* __restrict__ b_dec1,
                   const float* __restrict__ W_dec2, const float* __restrict__ b_dec2,
                   float* __restrict__ out)   // f32: weights [0,2^26), samples at 2^26
{
  // LDS (bytes), main loop:
  //   h0 [2][16][68] @0      (8704)
  //   h1 [2][16][68] @8704   (8704)
  //   d1 [16][100]   @17408  (6400)
  //   lg [16][128]   @23808  (8192)
  //   bias1 [256]    @32000  (1024)
  //   keyw [64][2]   @33024  (512)   -> 33536 total
  // encoder overlay: zb [16][256]@0 (16384), mid [16][164]@16384 (10496)
  //                  encv [16][68]@0, xg0s [16][256]@16384
  __shared__ __align__(16) char buf[33536];
  float* h0b   = (float*)buf;
  float* h1b   = (float*)(buf + 8704);
  float* d1    = (float*)(buf + 17408);
  float* lg    = (float*)(buf + 23808);
  float* bias1 = (float*)(buf + 32000);
  u32*   keyw  = (u32*)  (buf + 33024);
  float* zb    = (float*)buf;
  float* mid   = (float*)(buf + 16384);
  float* encv  = (float*)buf;
  float* xg0s  = (float*)(buf + 16384);

  const int t = threadIdx.x;
  const int tile0 = blockIdx.x * TILE;

  // ---------------- encoder (once) ----------------
  {
    const float4* zsrc = (const float4*)(z + (size_t)tile0 * ZDIM);
    float4* zdst = (float4*)zb;
    #pragma unroll
    for (int i = 0; i < 4; ++i) zdst[t + 256 * i] = zsrc[t + 256 * i];
  }
  __syncthreads();

  if (t < EMID) {                      // mid = relu(zb @ W1^T + b1)
    float acc[TILE];
    float bb = b_enc1[t];
    #pragma unroll
    for (int b = 0; b < TILE; ++b) acc[b] = bb;
    const float4* wr = (const float4*)(W_enc1 + (size_t)t * ZDIM);
    #pragma unroll 2
    for (int k4 = 0; k4 < 64; ++k4){
      float4 w = wr[k4];
      #pragma unroll
      for (int b = 0; b < TILE; ++b){
        float4 v = ((const float4*)zb)[b * 64 + k4];
        acc[b] = dot4acc(w, v, acc[b]);
      }
    }
    #pragma unroll
    for (int b = 0; b < TILE; ++b) mid[b * 164 + t] = fmaxf(acc[b], 0.0f);
  }
  __syncthreads();

  if (t < HDIM) {                      // enc = mid @ W2^T + b2
    float acc[TILE];
    float bb = b_enc2[t];
    #pragma unroll
    for (int b = 0; b < TILE; ++b) acc[b] = bb;
    const float4* wr = (const float4*)(W_enc2 + (size_t)t * EMID);
    #pragma unroll 2
    for (int k4 = 0; k4 < 40; ++k4){
      float4 w = wr[k4];
      #pragma unroll
      for (int b = 0; b < TILE; ++b){
        float4 v = ((const float4*)mid)[b * 41 + k4];
        acc[b] = dot4acc(w, v, acc[b]);
      }
    }
    #pragma unroll
    for (int b = 0; b < TILE; ++b) encv[b * 68 + t] = acc[b];
  }
  __syncthreads();

  {                                    // xg0 = enc @ Wih0^T + bih0 + bhh0
    float acc[TILE];
    float bb = b_ih0[t] + b_hh0[t];
    #pragma unroll
    for (int b = 0; b < TILE; ++b) acc[b] = bb;
    const float4* wr = (const float4*)(W_ih0 + (size_t)t * HDIM);
    #pragma unroll 2
    for (int k4 = 0; k4 < 16; ++k4){
      float4 w = wr[k4];
      #pragma unroll
      for (int b = 0; b < TILE; ++b){
        float4 v = ((const float4*)encv)[b * 17 + k4];
        acc[b] = dot4acc(w, v, acc[b]);
      }
    }
    #pragma unroll
    for (int b = 0; b < TILE; ++b) xg0s[b * 256 + t] = acc[b];
  }
  __syncthreads();

  // thread roles for LSTM phases: j = hidden unit, bg = batch group (4 each)
  const int w_id = t >> 6;
  const int l    = t & 63;
  const int j    = w_id * 16 + (l & 15);  // 0..63
  const int bg   = l >> 4;                // 0..3

  float xg0r[4][4];
  #pragma unroll
  for (int g = 0; g < 4; ++g)
    #pragma unroll
    for (int bi = 0; bi < 4; ++bi)
      xg0r[g][bi] = xg0s[(bg * 4 + bi) * 256 + g * 64 + j];
  __syncthreads();

  // init states (both h buffers), fused biases, per-step keys
  for (int i = t; i < 2 * 16 * 68; i += 256){ h0b[i] = 0.0f; h1b[i] = 0.0f; }
  bias1[t] = b_ih1[t] + b_hh1[t];
  if (t < SEQLEN) {
    u32 a0, a1;
    tf2x32(0u, 42u, 0u, (u32)t, a0, a1);   // partitionable split of key(42)
    keyw[2 * t] = a0; keyw[2 * t + 1] = a1;
  }
  float c0r[4], c1r[4];
  #pragma unroll
  for (int bi = 0; bi < 4; ++bi){ c0r[bi] = 0.0f; c1r[bi] = 0.0f; }
  __syncthreads();

  const float4* Whh0_4 = (const float4*)W_hh0;
  const float4* Wih1_4 = (const float4*)W_ih1;
  const float4* Whh1_4 = (const float4*)W_hh1;

  for (int s = 0; s < SEQLEN; ++s){
    const int cur = s & 1, prv = cur ^ 1;
    float* h0c = h0b + cur * (16 * 68);
    float* h0p = h0b + prv * (16 * 68);
    float* h1c = h1b + cur * (16 * 68);
    float* h1p = h1b + prv * (16 * 68);

    // ---------- A: layer 0 (reads h0p, writes h0c) ----------
    float acc[4][4];
    #pragma unroll
    for (int g = 0; g < 4; ++g)
      #pragma unroll
      for (int bi = 0; bi < 4; ++bi) acc[g][bi] = xg0r[g][bi];

    #pragma unroll 2
    for (int k4 = 0; k4 < 16; ++k4){
      float4 wv[4];
      #pragma unroll
      for (int g = 0; g < 4; ++g) wv[g] = Whh0_4[(g * 64 + j) * 16 + k4];
      #pragma unroll
      for (int bi = 0; bi < 4; ++bi){
        float4 hv = ((const float4*)h0p)[(bg * 4 + bi) * 17 + k4];
        #pragma unroll
        for (int g = 0; g < 4; ++g) acc[g][bi] = dot4acc(wv[g], hv, acc[g][bi]);
      }
    }
    #pragma unroll
    for (int bi = 0; bi < 4; ++bi){
      float ig = sigmf(acc[0][bi]);
      float fg = sigmf(acc[1][bi]);
      float gg = tanhf(acc[2][bi]);
      float og = sigmf(acc[3][bi]);
      float c  = fg * c0r[bi] + ig * gg;
      c0r[bi]  = c;
      h0c[(bg * 4 + bi) * 68 + j] = og * tanhf(c);
    }
    __syncthreads();   // 1: h0c visible

    // ---------- B: layer 1 (reads h0c, h1p, writes h1c) ----------
    #pragma unroll
    for (int g = 0; g < 4; ++g){
      float bb = bias1[g * 64 + j];
      #pragma unroll
      for (int bi = 0; bi < 4; ++bi) acc[g][bi] = bb;
    }
    #pragma unroll 2
    for (int k4 = 0; k4 < 16; ++k4){
      float4 wv[4];
      #pragma unroll
      for (int g = 0; g < 4; ++g) wv[g] = Wih1_4[(g * 64 + j) * 16 + k4];
      #pragma unroll
      for (int bi = 0; bi < 4; ++bi){
        float4 hv = ((const float4*)h0c)[(bg * 4 + bi) * 17 + k4];
        #pragma unroll
        for (int g = 0; g < 4; ++g) acc[g][bi] = dot4acc(wv[g], hv, acc[g][bi]);
      }
    }
    #pragma unroll 2
    for (int k4 = 0; k4 < 16; ++k4){
      float4 wv[4];
      #pragma unroll
      for (int g = 0; g < 4; ++g) wv[g] = Whh1_4[(g * 64 + j) * 16 + k4];
      #pragma unroll
      for (int bi = 0; bi < 4; ++bi){
        float4 hv = ((const float4*)h1p)[(bg * 4 + bi) * 17 + k4];
        #pragma unroll
        for (int g = 0; g < 4; ++g) acc[g][bi] = dot4acc(wv[g], hv, acc[g][bi]);
      }
    }
    #pragma unroll
    for (int bi = 0; bi < 4; ++bi){
      float ig = sigmf(acc[0][bi]);
      float fg = sigmf(acc[1][bi]);
      float gg = tanhf(acc[2][bi]);
      float og = sigmf(acc[3][bi]);
      float c  = fg * c1r[bi] + ig * gg;
      c1r[bi]  = c;
      h1c[(bg * 4 + bi) * 68 + j] = og * tanhf(c);
    }
    __syncthreads();   // 2: h1c visible

    // ---------- C: dec1 = relu(h1 @ Wdec1^T + b) ----------
    if (t < 192){
      const int d  = t % 96;
      const int hf = t / 96;           // 2 halves x 8 batches
      float accd[8];
      float bb = b_dec1[d];
      #pragma unroll
      for (int q = 0; q < 8; ++q) accd[q] = bb;
      const float4* wr = (const float4*)(W_dec1 + (size_t)d * HDIM);
      #pragma unroll 2
      for (int k4 = 0; k4 < 16; ++k4){
        float4 w = wr[k4];
        #pragma unroll
        for (int q = 0; q < 8; ++q){
          float4 hv = ((const float4*)h1c)[(hf * 8 + q) * 17 + k4];
          accd[q] = dot4acc(w, hv, accd[q]);
        }
      }
      #pragma unroll
      for (int q = 0; q < 8; ++q) d1[(hf * 8 + q) * 100 + d] = fmaxf(accd[q], 0.0f);
    }
    __syncthreads();   // 3: d1 visible

    // ---------- D: dec2 logits ----------
    {
      const int n  = t & 127;
      const int hf = t >> 7;
      float accd[8];
      float bb = b_dec2[n];
      #pragma unroll
      for (int q = 0; q < 8; ++q) accd[q] = bb;
      const float4* wr = (const float4*)(W_dec2 + (size_t)n * DMID);
      #pragma unroll 2
      for (int k4 = 0; k4 < 24; ++k4){
        float4 w = wr[k4];
        #pragma unroll
        for (int q = 0; q < 8; ++q){
          float4 dv = ((const float4*)d1)[(hf * 8 + q) * 25 + k4];
          accd[q] = dot4acc(w, dv, accd[q]);
        }
      }
      #pragma unroll
      for (int q = 0; q < 8; ++q) lg[(hf * 8 + q) * 128 + n] = accd[q];
    }
    __syncthreads();   // 4: lg visible

    // ---------- E: softmax + categorical sample (no trailing barrier) ----------
    {
      const int bl  = t >> 4;          // batch 0..15
      const int s16 = t & 15;          // 16 lanes per batch
      const int bgl = tile0 + bl;

      float lv[8];
      {
        const float4* lrow = (const float4*)(lg + bl * 128 + s16 * 8);
        float4 a = lrow[0], b = lrow[1];
        lv[0]=a.x; lv[1]=a.y; lv[2]=a.z; lv[3]=a.w;
        lv[4]=b.x; lv[5]=b.y; lv[6]=b.z; lv[7]=b.w;
      }
      float lmax = lv[0];
      #pragma unroll
      for (int i = 1; i < 8; ++i) lmax = fmaxf(lmax, lv[i]);
      #pragma unroll
      for (int m = 1; m < 16; m <<= 1) lmax = fmaxf(lmax, __shfl_xor(lmax, m));

      float esum = 0.0f; float ev[8];
      #pragma unroll
      for (int i = 0; i < 8; ++i){
        float e = expf(lv[i] - lmax);
        ev[i] = e; esum += e;
      }
      #pragma unroll
      for (int m = 1; m < 16; m <<= 1) esum += __shfl_xor(esum, m);
      float inv = 1.0f / esum;

      float4* wrow = (float4*)(out + (u64)bgl * (SEQLEN * NNEUR)
                                   + (u64)s * NNEUR + (u64)(s16 * 8));
      wrow[0] = make_float4(ev[0]*inv, ev[1]*inv, ev[2]*inv, ev[3]*inv);
      wrow[1] = make_float4(ev[4]*inv, ev[5]*inv, ev[6]*inv, ev[7]*inv);

      // gumbel argmax (threefry-partitionable bits = y0 ^ y1)
      const u32 kk0 = keyw[2 * s];
      const u32 kk1 = keyw[2 * s + 1];
      float vmax = -3.402823466e38f; int vidx = 0;
      #pragma unroll 2
      for (int i = 0; i < 8; ++i){
        const int n = s16 * 8 + i;
        u32 y0, y1;
        tf2x32(kk0, kk1, 0u, (u32)(bgl * 128 + n), y0, y1);
        u32 bits = y0 ^ y1;
        float f  = __uint_as_float((bits >> 9) | 0x3f800000u) - 1.0f;
        float u  = f + 1.1754943508222875e-38f;
        u = fmaxf(u, 1.1754943508222875e-38f);
        float gmb = -logf(-logf(u));
        float val = gmb + lv[i];
        if (val > vmax){ vmax = val; vidx = n; }
      }
      #pragma unroll
      for (int m = 1; m < 16; m <<= 1){
        float ov = __shfl_xor(vmax, m);
        int   oi = __shfl_xor(vidx, m);
        if (ov > vmax || (ov == vmax && oi < vidx)){ vmax = ov; vidx = oi; }
      }
      if (s16 == 0)
        out[(u64)NBATCH * SEQLEN * NNEUR + (u64)bgl * SEQLEN + (u64)s] = (float)vidx;
    }
    // no trailing barrier: next write to lg is 3 barriers away
  }
}

extern "C" void kernel_launch(void* const* d_in, const int* in_sizes, int n_in,
                              void* d_out, int out_size, void* d_ws, size_t ws_size,
                              hipStream_t stream) {
  (void)in_sizes; (void)n_in; (void)out_size; (void)d_ws; (void)ws_size;
  const float* z      = (const float*)d_in[0];
  // d_in[1]=score_tensor, d_in[2]=train: unused by the reference math
  const float* W_enc1 = (const float*)d_in[3];
  const float* b_enc1 = (const float*)d_in[4];
  const float* W_enc2 = (const float*)d_in[5];
  const float* b_enc2 = (const float*)d_in[6];
  const float* W_ih0  = (const float*)d_in[7];
  const float* W_hh0  = (const float*)d_in[8];
  const float* b_ih0  = (const float*)d_in[9];
  const float* b_hh0  = (const float*)d_in[10];
  const float* W_ih1  = (const float*)d_in[11];
  const float* W_hh1  = (const float*)d_in[12];
  const float* b_ih1  = (const float*)d_in[13];
  const float* b_hh1  = (const float*)d_in[14];
  const float* W_dec1 = (const float*)d_in[15];
  const float* b_dec1 = (const float*)d_in[16];
  const float* W_dec2 = (const float*)d_in[17];
  const float* b_dec2 = (const float*)d_in[18];

  float* out = (float*)d_out;

  dim3 grid(NBATCH / TILE);   // 512 blocks -> 2 blocks/CU
  dim3 blk(256);
  hipLaunchKernelGGL(bar_decoder_kernel, grid, blk, 0, stream,
                     z, W_enc1, b_enc1, W_enc2, b_enc2,
                     W_ih0, W_hh0, b_ih0, b_hh0,
                     W_ih1, W_hh1, b_ih1, b_hh1,
                     W_dec1, b_dec1, W_dec2, b_dec2,
                     out);
}

// Round 11
// 2586.874 us; speedup vs baseline: 4.0220x; 1.4112x over previous
//
#include <hip/hip_runtime.h>
#include <cstdint>
#include <cstddef>

typedef unsigned int u32;
typedef unsigned long long u64;

#define NBATCH 8192
#define SEQLEN 64
#define ZDIM   256
#define HDIM   64
#define NNEUR  128
#define EMID   160
#define DMID   96
#define TILE   32

#define LSTM_LDS 156672   // wB1 69632 + wB2 69632 + h0 8704 + h1 8704
#define DEC_LDS  137216   // w1 26112 + w2 51200 + keys 512 + d1 25600 + lg 33792
#define SOFF     67108864ULL

__device__ __forceinline__ u32 rotl32(u32 v, int s){ return (v << s) | (v >> (32 - s)); }

// Threefry2x32, 20 rounds — exact JAX schedule.
__device__ __forceinline__ void tf2x32(u32 k0, u32 k1, u32 x0, u32 x1, u32& y0, u32& y1){
  u32 ks2 = k0 ^ k1 ^ 0x1BD11BDAu;
  x0 += k0; x1 += k1;
#define TF_R(r) { x0 += x1; x1 = rotl32(x1, (r)); x1 ^= x0; }
  TF_R(13) TF_R(15) TF_R(26) TF_R(6)
  x0 += k1;  x1 += ks2 + 1u;
  TF_R(17) TF_R(29) TF_R(16) TF_R(24)
  x0 += ks2; x1 += k0 + 2u;
  TF_R(13) TF_R(15) TF_R(26) TF_R(6)
  x0 += k0;  x1 += k1 + 3u;
  TF_R(17) TF_R(29) TF_R(16) TF_R(24)
  x0 += k1;  x1 += ks2 + 4u;
  TF_R(13) TF_R(15) TF_R(26) TF_R(6)
  x0 += ks2; x1 += k0 + 5u;
#undef TF_R
  y0 = x0; y1 = x1;
}

__device__ __forceinline__ float sigmf(float x){ return 1.0f / (1.0f + expf(-x)); }

__device__ __forceinline__ float dot4acc(float4 w, float4 v, float a){
  a = fmaf(w.x, v.x, a); a = fmaf(w.y, v.y, a);
  a = fmaf(w.z, v.z, a); a = fmaf(w.w, v.w, a);
  return a;
}

// ---------------------------------------------------------------------------
// Kernel 1: encoder + 2-layer LSTM. Stores h1(b,s) into out[b*8192+s*128+0..63]
// (the first half of the weight row that kernel 2 will overwrite in place).
// ---------------------------------------------------------------------------
__global__ void __launch_bounds__(512, 1)
lstm_kernel(const float* __restrict__ z,
            const float* __restrict__ W_enc1, const float* __restrict__ b_enc1,
            const float* __restrict__ W_enc2, const float* __restrict__ b_enc2,
            const float* __restrict__ W_ih0,  const float* __restrict__ W_hh0,
            const float* __restrict__ b_ih0,  const float* __restrict__ b_hh0,
            const float* __restrict__ W_ih1,  const float* __restrict__ W_hh1,
            const float* __restrict__ b_ih1,  const float* __restrict__ b_hh1,
            float* __restrict__ out)
{
  extern __shared__ __align__(16) char dyn[];
  float4* wB1q = (float4*)dyn;                // W_ih1, 256 rows x 17 float4 (pad)
  float4* wB2q = (float4*)(dyn + 69632);      // W_hh1, 256 rows x 17 float4
  float*  h0f  = (float*)(dyn + 139264);      // [32][68]
  float4* h0q  = (float4*)(dyn + 139264);
  float*  h1f  = (float*)(dyn + 147968);      // [32][68]
  float4* h1q  = (float4*)(dyn + 147968);
  float*  mid  = (float*)dyn;                 // encoder overlay [32][164]
  float*  encv = (float*)(dyn + 139264);      // encoder overlay [32][68] (h0 region)

  const int t     = threadIdx.x;
  const int tile0 = blockIdx.x * TILE;
  const int l  = t & 63;
  const int w  = t >> 6;
  const int j  = ((w & 3) << 4) | (l & 15);   // hidden unit 0..63
  const int bh = w >> 2;                      // batch half 0..1
  const int bs = l >> 4;                      // batch sub-group 0..3

  // ---- encoder: mid = relu(z @ Wenc1^T + b1) ----
  if (t < EMID) {
    float acc[TILE];
    float bb = b_enc1[t];
    #pragma unroll
    for (int b = 0; b < TILE; ++b) acc[b] = bb;
    const float4* wr = (const float4*)(W_enc1 + (size_t)t * ZDIM);
    #pragma unroll 2
    for (int k4 = 0; k4 < 64; ++k4){
      float4 wv = wr[k4];
      for (int b = 0; b < TILE; ++b){
        float4 zv = *(const float4*)(z + (size_t)(tile0 + b) * ZDIM + k4 * 4);
        acc[b] = dot4acc(wv, zv, acc[b]);
      }
    }
    #pragma unroll
    for (int b = 0; b < TILE; ++b) mid[b * 164 + t] = fmaxf(acc[b], 0.0f);
  }
  __syncthreads();

  // ---- enc = mid @ Wenc2^T + b2 -> encv ----
  if (t < HDIM) {
    float acc[TILE];
    float bb = b_enc2[t];
    #pragma unroll
    for (int b = 0; b < TILE; ++b) acc[b] = bb;
    const float4* wr = (const float4*)(W_enc2 + (size_t)t * EMID);
    #pragma unroll 2
    for (int k4 = 0; k4 < 40; ++k4){
      float4 wv = wr[k4];
      for (int b = 0; b < TILE; ++b){
        float4 v = *(const float4*)(mid + b * 164 + k4 * 4);
        acc[b] = dot4acc(wv, v, acc[b]);
      }
    }
    #pragma unroll
    for (int b = 0; b < TILE; ++b) encv[b * 68 + t] = acc[b];
  }
  __syncthreads();

  // ---- xg0 regs + bias regs + weight staging (disjoint LDS regions) ----
  float xg0r[4][4];
  #pragma unroll
  for (int g = 0; g < 4; ++g){
    const int row = g * 64 + j;
    const float bbias = b_ih0[row] + b_hh0[row];
    float a[4] = {bbias, bbias, bbias, bbias};
    const float4* wr = (const float4*)(W_ih0 + (size_t)row * HDIM);
    #pragma unroll 4
    for (int k4 = 0; k4 < 16; ++k4){
      float4 wv = wr[k4];
      #pragma unroll
      for (int bi = 0; bi < 4; ++bi){
        float4 ev = *(const float4*)(encv + (bh * 16 + bs * 4 + bi) * 68 + k4 * 4);
        a[bi] = dot4acc(wv, ev, a[bi]);
      }
    }
    #pragma unroll
    for (int bi = 0; bi < 4; ++bi) xg0r[g][bi] = a[bi];
  }
  float bias1r[4];
  #pragma unroll
  for (int g = 0; g < 4; ++g) bias1r[g] = b_ih1[g * 64 + j] + b_hh1[g * 64 + j];

  for (int i = t; i < 4096; i += 512){
    int row = i >> 4, k = i & 15;
    wB1q[row * 17 + k] = ((const float4*)W_ih1)[i];
    wB2q[row * 17 + k] = ((const float4*)W_hh1)[i];
  }
  __syncthreads();   // encv dead, staging done

  for (int i = t; i < 2176; i += 512){ h0f[i] = 0.0f; h1f[i] = 0.0f; }
  float c0r[4] = {0,0,0,0}, c1r[4] = {0,0,0,0};
  __syncthreads();

  const float4* Whh0q = (const float4*)W_hh0;
  float4* outq = (float4*)out;

  for (int s = 0; s < SEQLEN; ++s){
    // ---- A: layer0 (reads h0 old, Whh0 from L2) ----
    float acc[4][4];
    #pragma unroll
    for (int g = 0; g < 4; ++g)
      #pragma unroll
      for (int bi = 0; bi < 4; ++bi) acc[g][bi] = xg0r[g][bi];
    #pragma unroll 4
    for (int k4 = 0; k4 < 16; ++k4){
      float4 wv[4];
      #pragma unroll
      for (int g = 0; g < 4; ++g) wv[g] = Whh0q[(g * 64 + j) * 16 + k4];
      #pragma unroll
      for (int bi = 0; bi < 4; ++bi){
        float4 hv = h0q[(bh * 16 + bs * 4 + bi) * 17 + k4];
        #pragma unroll
        for (int g = 0; g < 4; ++g) acc[g][bi] = dot4acc(wv[g], hv, acc[g][bi]);
      }
    }
    float hn[4];
    #pragma unroll
    for (int bi = 0; bi < 4; ++bi){
      float ig = sigmf(acc[0][bi]);
      float fg = sigmf(acc[1][bi]);
      float gg = tanhf(acc[2][bi]);
      float og = sigmf(acc[3][bi]);
      float c  = fg * c0r[bi] + ig * gg;
      c0r[bi]  = c;
      hn[bi]   = og * tanhf(c);
    }
    __syncthreads();   // 1: all h0-old reads done
    #pragma unroll
    for (int bi = 0; bi < 4; ++bi) h0f[(bh * 16 + bs * 4 + bi) * 68 + j] = hn[bi];
    __syncthreads();   // 2: h0 new visible

    // ---- B: layer1 (weights from LDS) ----
    #pragma unroll
    for (int g = 0; g < 4; ++g)
      #pragma unroll
      for (int bi = 0; bi < 4; ++bi) acc[g][bi] = bias1r[g];
    #pragma unroll 4
    for (int k4 = 0; k4 < 16; ++k4){
      float4 wv[4];
      #pragma unroll
      for (int g = 0; g < 4; ++g) wv[g] = wB1q[(g * 64 + j) * 17 + k4];
      #pragma unroll
      for (int bi = 0; bi < 4; ++bi){
        float4 hv = h0q[(bh * 16 + bs * 4 + bi) * 17 + k4];
        #pragma unroll
        for (int g = 0; g < 4; ++g) acc[g][bi] = dot4acc(wv[g], hv, acc[g][bi]);
      }
    }
    #pragma unroll 4
    for (int k4 = 0; k4 < 16; ++k4){
      float4 wv[4];
      #pragma unroll
      for (int g = 0; g < 4; ++g) wv[g] = wB2q[(g * 64 + j) * 17 + k4];
      #pragma unroll
      for (int bi = 0; bi < 4; ++bi){
        float4 hv = h1q[(bh * 16 + bs * 4 + bi) * 17 + k4];
        #pragma unroll
        for (int g = 0; g < 4; ++g) acc[g][bi] = dot4acc(wv[g], hv, acc[g][bi]);
      }
    }
    #pragma unroll
    for (int bi = 0; bi < 4; ++bi){
      float ig = sigmf(acc[0][bi]);
      float fg = sigmf(acc[1][bi]);
      float gg = tanhf(acc[2][bi]);
      float og = sigmf(acc[3][bi]);
      float c  = fg * c1r[bi] + ig * gg;
      c1r[bi]  = c;
      hn[bi]   = og * tanhf(c);
    }
    __syncthreads();   // 3: all h1-old reads done
    #pragma unroll
    for (int bi = 0; bi < 4; ++bi) h1f[(bh * 16 + bs * 4 + bi) * 68 + j] = hn[bi];
    __syncthreads();   // 4: h1 new visible

    // ---- stash h1 tile to global (coalesced), in-place at the weight rows ----
    {
      const int row = t >> 4;     // 0..31
      const int k   = t & 15;     // 0..15 float4
      outq[(u64)(tile0 + row) * 2048 + (u64)s * 32 + k] = h1q[row * 17 + k];
    }
  }
}

// ---------------------------------------------------------------------------
// Kernel 2: decoder + softmax + categorical sampling. Reads h1 rows in place,
// overwrites them with the softmax weights; writes samples at SOFF.
// Per block: 32 batches; per tile: one batch (64 rows = all steps).
// ---------------------------------------------------------------------------
__global__ void __launch_bounds__(512, 1)
dec_kernel(const float* __restrict__ W_dec1, const float* __restrict__ b_dec1,
           const float* __restrict__ W_dec2, const float* __restrict__ b_dec2,
           float* __restrict__ out)
{
  extern __shared__ __align__(16) char dyn[];
  float4* w1q  = (float4*)dyn;                // 96 rows x 17 f4 (pad)
  float4* w2q  = (float4*)(dyn + 26112);      // 128 rows x 25 f4 (pad)
  u32*    keyw = (u32*)  (dyn + 77312);
  float*  d1f  = (float*)(dyn + 77824);       // [64][100]
  float4* d1q  = (float4*)(dyn + 77824);
  float*  lgf  = (float*)(dyn + 103424);      // [64][132] (pad)

  const int t = threadIdx.x;
  const int l = t & 63;
  const int w = t >> 6;

  for (int i = t; i < 1536; i += 512){ int r = i >> 4, k = i & 15; w1q[r * 17 + k] = ((const float4*)W_dec1)[i]; }
  for (int i = t; i < 3072; i += 512){ int r = i / 24, k = i - r * 24; w2q[r * 25 + k] = ((const float4*)W_dec2)[i]; }
  if (t < SEQLEN){
    u32 a0, a1;
    tf2x32(0u, 42u, 0u, (u32)t, a0, a1);   // partitionable split of key(42)
    keyw[2 * t] = a0; keyw[2 * t + 1] = a1;
  }
  __syncthreads();

  float4* outq = (float4*)out;

  for (int bt = 0; bt < 32; ++bt){
    const int bb = blockIdx.x * 32 + bt;

    // h row of (batch bb, step l) into registers (each wave covers all 64 steps)
    float4 hr[16];
    #pragma unroll
    for (int k = 0; k < 16; ++k) hr[k] = outq[(u64)bb * 2048 + (u64)l * 32 + k];

    // ---- C: d1 = relu(h @ Wdec1^T + b). wave w owns dn = w*12..+11 (uniform) ----
    #pragma unroll 1
    for (int dnI = 0; dnI < 12; ++dnI){
      const int dn = w * 12 + dnI;
      float a = b_dec1[dn];
      #pragma unroll
      for (int k4 = 0; k4 < 16; ++k4) a = dot4acc(w1q[dn * 17 + k4], hr[k4], a);
      d1f[l * 100 + dn] = fmaxf(a, 0.0f);
    }
    __syncthreads();   // 1

    // ---- D: logits = d1 @ Wdec2^T + b. wave w owns n = w*16..+15 (uniform) ----
    float4 d1r[24];
    #pragma unroll
    for (int k4 = 0; k4 < 24; ++k4) d1r[k4] = d1q[l * 25 + k4];
    #pragma unroll 1
    for (int nI = 0; nI < 16; ++nI){
      const int n = w * 16 + nI;
      float a = b_dec2[n];
      #pragma unroll
      for (int k4 = 0; k4 < 24; ++k4) a = dot4acc(w2q[n * 25 + k4], d1r[k4], a);
      lgf[l * 132 + n] = a;
    }
    __syncthreads();   // 2

    // ---- E: softmax + categorical sample (verified R6 structure, 8 lanes/row) ----
    {
      const int row = t >> 3;          // step s = row
      const int s8  = t & 7;
      float lv[16];
      {
        const float4* lrow = (const float4*)(lgf + row * 132 + s8 * 16);
        float4 a = lrow[0], b2 = lrow[1], c2 = lrow[2], d2 = lrow[3];
        lv[0]=a.x;  lv[1]=a.y;  lv[2]=a.z;  lv[3]=a.w;
        lv[4]=b2.x; lv[5]=b2.y; lv[6]=b2.z; lv[7]=b2.w;
        lv[8]=c2.x; lv[9]=c2.y; lv[10]=c2.z; lv[11]=c2.w;
        lv[12]=d2.x; lv[13]=d2.y; lv[14]=d2.z; lv[15]=d2.w;
      }
      float lmax = -3.402823466e38f;
      #pragma unroll
      for (int i = 0; i < 16; ++i) lmax = fmaxf(lmax, lv[i]);
      #pragma unroll
      for (int m = 1; m < 8; m <<= 1) lmax = fmaxf(lmax, __shfl_xor(lmax, m));

      float esum = 0.0f; float ev[16];
      #pragma unroll
      for (int i = 0; i < 16; ++i){
        float e = expf(lv[i] - lmax);
        ev[i] = e; esum += e;
      }
      #pragma unroll
      for (int m = 1; m < 8; m <<= 1) esum += __shfl_xor(esum, m);
      float inv = 1.0f / esum;

      #pragma unroll
      for (int q = 0; q < 4; ++q)
        outq[(u64)bb * 2048 + (u64)row * 32 + s8 * 4 + q] =
          make_float4(ev[4*q]*inv, ev[4*q+1]*inv, ev[4*q+2]*inv, ev[4*q+3]*inv);

      const u32 kk0 = keyw[2 * row];
      const u32 kk1 = keyw[2 * row + 1];
      float vmax = -3.402823466e38f; int vidx = 0;
      #pragma unroll 2
      for (int i = 0; i < 16; ++i){
        const int n = s8 * 16 + i;
        u32 y0, y1;
        tf2x32(kk0, kk1, 0u, (u32)(bb * 128 + n), y0, y1);
        u32 bits = y0 ^ y1;
        float f  = __uint_as_float((bits >> 9) | 0x3f800000u) - 1.0f;
        float u  = f + 1.1754943508222875e-38f;   // f*(1-tiny)+tiny in f32
        u = fmaxf(u, 1.1754943508222875e-38f);
        float gmb = -logf(-logf(u));
        float val = gmb + lv[i];
        if (val > vmax){ vmax = val; vidx = n; }
      }
      #pragma unroll
      for (int m = 1; m < 8; m <<= 1){
        float ov = __shfl_xor(vmax, m);
        int   oi = __shfl_xor(vidx, m);
        if (ov > vmax || (ov == vmax && oi < vidx)){ vmax = ov; vidx = oi; }
      }
      if (s8 == 0)
        out[SOFF + (u64)bb * SEQLEN + (u64)row] = (float)vidx;
    }
    // no trailing barrier: next writes to d1f/lgf are >=1 barrier away
  }
}

extern "C" void kernel_launch(void* const* d_in, const int* in_sizes, int n_in,
                              void* d_out, int out_size, void* d_ws, size_t ws_size,
                              hipStream_t stream) {
  (void)in_sizes; (void)n_in; (void)out_size; (void)d_ws; (void)ws_size;
  const float* z      = (const float*)d_in[0];
  const float* W_enc1 = (const float*)d_in[3];
  const float* b_enc1 = (const float*)d_in[4];
  const float* W_enc2 = (const float*)d_in[5];
  const float* b_enc2 = (const float*)d_in[6];
  const float* W_ih0  = (const float*)d_in[7];
  const float* W_hh0  = (const float*)d_in[8];
  const float* b_ih0  = (const float*)d_in[9];
  const float* b_hh0  = (const float*)d_in[10];
  const float* W_ih1  = (const float*)d_in[11];
  const float* W_hh1  = (const float*)d_in[12];
  const float* b_ih1  = (const float*)d_in[13];
  const float* b_hh1  = (const float*)d_in[14];
  const float* W_dec1 = (const float*)d_in[15];
  const float* b_dec1 = (const float*)d_in[16];
  const float* W_dec2 = (const float*)d_in[17];
  const float* b_dec2 = (const float*)d_in[18];

  float* out = (float*)d_out;

  (void)hipFuncSetAttribute((const void*)lstm_kernel,
                            hipFuncAttributeMaxDynamicSharedMemorySize, LSTM_LDS);
  (void)hipFuncSetAttribute((const void*)dec_kernel,
                            hipFuncAttributeMaxDynamicSharedMemorySize, DEC_LDS);

  hipLaunchKernelGGL(lstm_kernel, dim3(NBATCH / TILE), dim3(512), LSTM_LDS, stream,
                     z, W_enc1, b_enc1, W_enc2, b_enc2,
                     W_ih0, W_hh0, b_ih0, b_hh0,
                     W_ih1, W_hh1, b_ih1, b_hh1, out);

  hipLaunchKernelGGL(dec_kernel, dim3(256), dim3(512), DEC_LDS, stream,
                     W_dec1, b_dec1, W_dec2, b_dec2, out);
}